// Round 3
// baseline (430.626 us; speedup 1.0000x reference)
//
#include <hip/hip_runtime.h>
#include <hip/hip_fp16.h>

// RGCN: out = hetero(relu(hetero(x, W1,b1)), W2,b2)
// BOTH layers are gather-first + MFMA GEMM:
//   L1: Zagg1 = phased-gather(x16)   [N,384]; H = relu(bsum1 + Zagg1 @ W1)  (fp16, panel-major)
//   L2: Zagg2 = phased-gather(H16p)  [N,384]; out = bsum2 + Zagg2 @ W2      (fp32)
// Phased gather (R13-R15 arc): gathered matrix stored panel-major [4][N][32]
//   (3.2MB/panel < 4MiB per-XCD L2). R14 lesson: grid-ordered passes overlap
//   (in-flight blocks ~= pass size) -> 2 panels thrash L2 (+74MB refetch).
//   R15: ONE LAUNCH PER PANEL (stream-serialized) -> exactly one panel hot.
//   Shape: 16-lane group per node (dword/lane = 64B row), 4 nodes/wave,
//   8-edge unroll (8 loads in flight/lane), no cross-lane reduce.
// Layer 2 gather-first (not GEMM-first): H panels are L2-resident and shared
//   across relations; Y2 (19.2MB) never was. gather_out + gemmY deleted.
// BK=1024 CSR build: radix partition, zero global atomics.

constexpr int N   = 50000;
constexpr int R   = 3;
constexpr int IN  = 128;
constexpr int HID = 128;
constexpr int OUT = 64;
constexpr int M   = R * N;
constexpr int BK  = 1024;
constexpr int NBKT = (M + BK - 1) / BK;    // 147
constexpr int CHUNK = 8192;
constexpr int KB  = 24;                    // 384/16 k-blocks for MFMA
constexpr int CVT_N4 = N * IN / 4;         // 1.6M float4 groups
constexpr int WPK   = 6 * KB * 64;         // 9216 weight frags
constexpr int WPK_B = (WPK + 255) / 256;   // 36 blocks
constexpr int NPASS = 4;                   // column panels for gathers
constexpr int QC    = IN / NPASS;          // 32 cols per panel

typedef _Float16 half8 __attribute__((ext_vector_type(8)));
typedef float floatx16 __attribute__((ext_vector_type(16)));

// ---- prep: bsum (block 0) + wpack (blocks 1..36) + x fp32->fp16 (rest) ----
// x16 layout: panel-major [NPASS][N][QC] so a 32-col panel is 3.2MB contiguous.
__global__ void prep_kernel(const float* __restrict__ x,
                            const float* __restrict__ W1, const float* __restrict__ W2,
                            const float* __restrict__ b1, const float* __restrict__ b2,
                            __half* __restrict__ x16,
                            __half* __restrict__ F1, __half* __restrict__ F2,
                            float* __restrict__ bsum1, float* __restrict__ bsum2) {
    int b = blockIdx.x;
    if (b == 0) {
        int t = threadIdx.x;
        if (t < HID) bsum1[t] = b1[t] + b1[HID + t] + b1[2 * HID + t];
        if (t < OUT) bsum2[t] = b2[t] + b2[OUT + t] + b2[2 * OUT + t];
        return;
    }
    if (b <= WPK_B) {
        int idx = (b - 1) * 256 + threadIdx.x;
        if (idx < 4 * KB * 64) {
            int nt = idx / (KB * 64), rem = idx % (KB * 64);
            int kb = rem / 64, lane = rem % 64;
            int c = nt * 32 + (lane & 31);
            int k0 = kb * 16 + (lane >> 5) * 8;
            __half h[8];
#pragma unroll
            for (int j = 0; j < 8; j++) h[j] = __float2half_rn(W1[(k0 + j) * 128 + c]);
            *(uint4*)(F1 + (size_t)idx * 8) = *(uint4*)h;
        } else if (idx < 6 * KB * 64) {
            int i2 = idx - 4 * KB * 64;
            int nt = i2 / (KB * 64), rem = i2 % (KB * 64);
            int kb = rem / 64, lane = rem % 64;
            int c = nt * 32 + (lane & 31);
            int k0 = kb * 16 + (lane >> 5) * 8;
            __half h[8];
#pragma unroll
            for (int j = 0; j < 8; j++) h[j] = __float2half_rn(W2[(k0 + j) * 64 + c]);
            *(uint4*)(F2 + (size_t)i2 * 8) = *(uint4*)h;
        }
        return;
    }
    int i = (b - 1 - WPK_B) * 256 + threadIdx.x;
    if (i >= CVT_N4) return;
    float4 v = ((const float4*)x)[i];
    __half2 a = __floats2half2_rn(v.x, v.y);
    __half2 c = __floats2half2_rn(v.z, v.w);
    uint2 o;
    o.x = *(unsigned*)&a;
    o.y = *(unsigned*)&c;
    int n  = i >> 5;            // 32 float4-groups per row
    int c4 = (i & 31) * 4;      // starting col (multiple of 4)
    int q  = c4 >> 5;           // panel
    int cq = c4 & 31;           // col within panel
    *(uint2*)(x16 + (size_t)q * N * QC + (size_t)n * QC + cq) = o;
}

// ---- P1: coarse bucket histograms per edge-chunk ----
__global__ __launch_bounds__(256) void p1_kernel(const int* __restrict__ src,
                                                 const int* __restrict__ dst,
                                                 int E, int RE, int nb,
                                                 int* __restrict__ bh) {
    __shared__ int hd[NBKT], hs[NBKT];
    for (int i = threadIdx.x; i < NBKT; i += 256) { hd[i] = 0; hs[i] = 0; }
    __syncthreads();
    int beg = blockIdx.x * CHUNK, end = min(RE, beg + CHUNK);
    for (int g = beg + (int)threadIdx.x; g < end; g += 256) {
        int rb = ((g >= E) + (g >= 2 * E)) * N;
        atomicAdd(&hd[(rb + dst[g]) >> 10], 1);
        atomicAdd(&hs[(rb + src[g]) >> 10], 1);
    }
    __syncthreads();
    for (int i = threadIdx.x; i < NBKT; i += 256) {
        bh[i * nb + blockIdx.x] = hd[i];
        bh[(NBKT + i) * nb + blockIdx.x] = hs[i];
    }
}

// ---- 2-stage exclusive scan (stage-3 folded into consumers) ----
__global__ void scan1_kernel(const int* __restrict__ in, int* __restrict__ out,
                             int* __restrict__ partials, int L) {
    __shared__ int lds[1024];
    int t = threadIdx.x;
    int idx = blockIdx.x * 1024 + t;
    int v = (idx < L) ? in[idx] : 0;
    lds[t] = v;
    __syncthreads();
    for (int off = 1; off < 1024; off <<= 1) {
        int u = (t >= off) ? lds[t - off] : 0;
        __syncthreads();
        lds[t] += u;
        __syncthreads();
    }
    if (idx < L) out[idx] = lds[t] - v;
    if (t == 1023) partials[blockIdx.x] = lds[1023];
}

__global__ void scan2_kernel(int* __restrict__ partials, int nb1) {
    __shared__ int lds[256];
    int t = threadIdx.x;
    int v = (t < nb1) ? partials[t] : 0;
    lds[t] = v;
    __syncthreads();
    for (int off = 1; off < 256; off <<= 1) {
        int u = (t >= off) ? lds[t - off] : 0;
        __syncthreads();
        lds[t] += u;
        __syncthreads();
    }
    if (t < nb1) partials[t] = lds[t] - v;
}

// ---- P3: scatter edges into bucket-sorted buffers via LDS cursors ----
// ebd[pos] = (src<<10)|(dkey&1023); ebs[pos] = skey&1023 (ushort)
__global__ __launch_bounds__(256) void p3_kernel(const int* __restrict__ src,
                                                 const int* __restrict__ dst,
                                                 int E, int RE, int nb,
                                                 const int* __restrict__ scanv,
                                                 const int* __restrict__ partials,
                                                 int* __restrict__ ebd,
                                                 unsigned short* __restrict__ ebs) {
    __shared__ int cd[NBKT], cs[NBKT];
    for (int i = threadIdx.x; i < NBKT; i += 256) {
        int id = i * nb + blockIdx.x;
        int is = (NBKT + i) * nb + blockIdx.x;
        cd[i] = scanv[id] + partials[id >> 10];
        cs[i] = scanv[is] + partials[is >> 10] - RE;
    }
    __syncthreads();
    int beg = blockIdx.x * CHUNK, end = min(RE, beg + CHUNK);
    for (int g = beg + (int)threadIdx.x; g < end; g += 256) {
        int rb = ((g >= E) + (g >= 2 * E)) * N;
        int s  = src[g];
        int kd = rb + dst[g];
        int pd = atomicAdd(&cd[kd >> 10], 1);
        ebd[pd] = (s << 10) | (kd & 1023);
        int ks = rb + s;
        int ps = atomicAdd(&cs[ks >> 10], 1);
        ebs[ps] = (unsigned short)(ks & 1023);
    }
}

// ---- PB-S: per s-bucket exact histogram -> rs_out ----
__global__ __launch_bounds__(1024) void pbs_kernel(const int* __restrict__ scanv,
                                                   const int* __restrict__ partials,
                                                   int nb, int RE,
                                                   const unsigned short* __restrict__ ebs,
                                                   float* __restrict__ rs_out) {
    __shared__ int cnt[BK];
    int t = threadIdx.x;
    int k = blockIdx.x;
    int i0 = (NBKT + k) * nb;
    int segbeg = scanv[i0] + partials[i0 >> 10] - RE;
    int segend;
    if (k == NBKT - 1) segend = RE;
    else {
        int i1 = i0 + nb;
        segend = scanv[i1] + partials[i1 >> 10] - RE;
    }
    cnt[t] = 0;
    __syncthreads();
    for (int e = segbeg + t; e < segend; e += 1024)
        atomicAdd(&cnt[(int)ebs[e]], 1);
    __syncthreads();
    int slot = k * BK + t;
    if (slot < M) rs_out[slot] = rsqrtf((float)(cnt[t] + 1));
}

// ---- PB-D: per d-bucket histogram -> row_ptr/rs_in, scatter coeff-packed esrc ----
__global__ __launch_bounds__(1024) void pbd_kernel(const int* __restrict__ scanv,
                                                   const int* __restrict__ partials,
                                                   int nb, int RE,
                                                   const int* __restrict__ ebd,
                                                   const float* __restrict__ rs_out,
                                                   int* __restrict__ row_ptr,
                                                   float* __restrict__ rs_in,
                                                   unsigned int* __restrict__ esrc) {
    __shared__ int cnt[BK];
    __shared__ int cur[BK];
    int t = threadIdx.x;
    int k = blockIdx.x;
    int i0 = k * nb;
    int segbeg = scanv[i0] + partials[i0 >> 10];
    int segend;
    if (k == NBKT - 1) segend = RE;
    else {
        int i1 = (k + 1) * nb;
        segend = scanv[i1] + partials[i1 >> 10];
    }
    cnt[t] = 0;
    __syncthreads();
    for (int e = segbeg + t; e < segend; e += 1024)
        atomicAdd(&cnt[ebd[e] & 1023], 1);
    __syncthreads();
    int slot = k * BK + t;
    int c = cnt[t];
    cur[t] = c;
    __syncthreads();
    for (int off = 1; off < 1024; off <<= 1) {
        int u = (t >= off) ? cur[t - off] : 0;
        __syncthreads();
        cur[t] += u;
        __syncthreads();
    }
    int excl = cur[t] - c;
    if (slot < M) {
        row_ptr[slot] = segbeg + excl;
        rs_in[slot] = rsqrtf((float)(c + 1));   // +1 self-loop
    }
    if (k == NBKT - 1 && t == 0) row_ptr[M] = RE;
    __syncthreads();
    cur[t] = segbeg + excl;
    __syncthreads();
    for (int e = segbeg + t; e < segend; e += 1024) {
        int v = ebd[e];
        int key = k * BK + (v & 1023);
        int r = (key >= 2 * N) + (key >= N);
        unsigned s = (unsigned)(v >> 10);
        int pos = atomicAdd(&cur[v & 1023], 1);
        __half h = __float2half_rn(rs_out[r * N + s]);
        esrc[pos] = s | ((unsigned)__half_as_ushort(h) << 16);
    }
}

// ---- phased gather (shared by both layers): ONE LAUNCH PER PANEL.
// Xq = panel base ([N][QC] fp16), Zq = Z16 + q*QC (row stride 384).
// 16-lane group per node (dword/lane = 64B row), 4 nodes/wave, 16 nodes/block,
// 8-edge unroll (8 row loads in flight/lane), per-group loop exit, no reduce.
// Zq[n*384 + r*128 + cl*2] = rs_in*(sum_e coeff*Xq[s] + rs_out*Xq[n]). ----
__global__ __launch_bounds__(256) void gather_kernel(const __half* __restrict__ Xq,
                                                     const float* __restrict__ rs_in,
                                                     const float* __restrict__ rs_out,
                                                     const int* __restrict__ row_ptr,
                                                     const unsigned int* __restrict__ esrc,
                                                     __half* __restrict__ Zq) {
    int lane = threadIdx.x & 63;
    int wv = threadIdx.x >> 6;
    int g = lane >> 4;                        // node group 0..3
    int cl = lane & 15;                       // dword: panel cols cl*2, cl*2+1
    int n = blockIdx.x * 16 + wv * 4 + g;     // N % 16 == 0 -> always valid
    unsigned xn = *(const unsigned*)(Xq + (long)n * QC + cl * 2);
    const __half2 z2 = __float2half2_rn(0.f);
#pragma unroll
    for (int r = 0; r < R; r++) {
        int key = r * N + n;
        int beg = row_ptr[key], end = row_ptr[key + 1];
        __half2 acc = z2;
        for (int e = beg; e < end; e += 8) {
            unsigned u[8];
#pragma unroll
            for (int i = 0; i < 8; i++)
                u[i] = (e + i < end) ? esrc[e + i] : 0u;   // coeff bits 0 -> adds 0
            unsigned y[8];
#pragma unroll
            for (int i = 0; i < 8; i++)
                y[i] = *(const unsigned*)(Xq + (long)(u[i] & 0xffffu) * QC + cl * 2);
#pragma unroll
            for (int i = 0; i < 8; i++) {
                __half2 cc = __half2half2(__ushort_as_half((unsigned short)(u[i] >> 16)));
                acc = __hfma2(*(__half2*)&y[i], cc, acc);
            }
        }
        __half2 cs = __float2half2_rn(rs_out[key]);
        acc = __hfma2(*(__half2*)&xn, cs, acc);
        __half2 ri = __float2half2_rn(rs_in[key]);
        acc = __hmul2(acc, ri);
        *(unsigned*)(Zq + (long)n * 384 + r * 128 + cl * 2) = *(unsigned*)&acc;
    }
}

// ---- layer-1 MFMA GEMM: H16p = fp16(relu(bias + Z16[N,384] @ W1)), stored
// PANEL-MAJOR [4][N][32] (panel = nt) so layer-2 gather can phase it.
// C/D map: col=lane&31, row=(reg&3)+8*(reg>>2)+4*(lane>>5)  [m74/m101 verified]
__global__ __launch_bounds__(256) void mfma_gemm1_kernel(const __half* __restrict__ Z16,
                                                         const __half* __restrict__ F,
                                                         const float* __restrict__ bias,
                                                         __half* __restrict__ H16p) {
    int wave = threadIdx.x >> 6, lane = threadIdx.x & 63;
    int m0 = blockIdx.x * 128 + wave * 32;
    int mr = min(m0 + (lane & 31), N - 1);
    const half8* A = (const half8*)(Z16 + (long)mr * 384 + (lane >> 5) * 8);
    const half8* B = (const half8*)F;
    floatx16 acc[4];
#pragma unroll
    for (int i = 0; i < 4; i++)
#pragma unroll
        for (int j = 0; j < 16; j++) acc[i][j] = 0.f;

    half8 a = A[0];
    for (int kb = 0; kb < KB; kb++) {
        half8 an = (kb < KB - 1) ? A[(kb + 1) * 2] : a;
#pragma unroll
        for (int nt = 0; nt < 4; nt++) {
            half8 b = B[(nt * KB + kb) * 64 + lane];
            acc[nt] = __builtin_amdgcn_mfma_f32_32x32x16_f16(a, b, acc[nt], 0, 0, 0);
        }
        a = an;
    }
    float bv[4];
#pragma unroll
    for (int nt = 0; nt < 4; nt++) bv[nt] = bias[nt * 32 + (lane & 31)];
    int rbase = m0 + 4 * (lane >> 5);
    int col0 = lane & 31;
#pragma unroll
    for (int nt = 0; nt < 4; nt++) {
#pragma unroll
        for (int reg = 0; reg < 16; reg++) {
            int row = rbase + (reg & 3) + 8 * (reg >> 2);
            if (row < N) {
                float v = fmaxf(acc[nt][reg] + bv[nt], 0.f);
                H16p[(size_t)nt * N * 32 + (long)row * 32 + col0] = __float2half_rn(v);
            }
        }
    }
}

// ---- layer-2 MFMA GEMM: out = bsum2 + Zagg2[N,384] @ W2 (fp32 out, no relu).
// Same structure as gemm1 with OUT=64 (nt 0..1); F2 kb-order matches the
// Zagg2 row layout [r0 cols | r1 | r2] (k-global = r*128 + col). ----
__global__ __launch_bounds__(256) void mfma_gemm2_kernel(const __half* __restrict__ Z16,
                                                         const __half* __restrict__ F,
                                                         const float* __restrict__ bias,
                                                         float* __restrict__ outp) {
    int wave = threadIdx.x >> 6, lane = threadIdx.x & 63;
    int m0 = blockIdx.x * 128 + wave * 32;
    int mr = min(m0 + (lane & 31), N - 1);
    const half8* A = (const half8*)(Z16 + (long)mr * 384 + (lane >> 5) * 8);
    const half8* B = (const half8*)F;
    floatx16 acc[2];
#pragma unroll
    for (int i = 0; i < 2; i++)
#pragma unroll
        for (int j = 0; j < 16; j++) acc[i][j] = 0.f;

    half8 a = A[0];
    for (int kb = 0; kb < KB; kb++) {
        half8 an = (kb < KB - 1) ? A[(kb + 1) * 2] : a;
#pragma unroll
        for (int nt = 0; nt < 2; nt++) {
            half8 b = B[(nt * KB + kb) * 64 + lane];
            acc[nt] = __builtin_amdgcn_mfma_f32_32x32x16_f16(a, b, acc[nt], 0, 0, 0);
        }
        a = an;
    }
    float bv[2];
#pragma unroll
    for (int nt = 0; nt < 2; nt++) bv[nt] = bias[nt * 32 + (lane & 31)];
    int rbase = m0 + 4 * (lane >> 5);
    int col0 = lane & 31;
#pragma unroll
    for (int nt = 0; nt < 2; nt++) {
#pragma unroll
        for (int reg = 0; reg < 16; reg++) {
            int row = rbase + (reg & 3) + 8 * (reg >> 2);
            if (row < N)
                outp[(long)row * 64 + nt * 32 + col0] = acc[nt][reg] + bv[nt];
        }
    }
}

extern "C" void kernel_launch(void* const* d_in, const int* in_sizes, int n_in,
                              void* d_out, int out_size, void* d_ws, size_t ws_size,
                              hipStream_t stream) {
    const float* x  = (const float*)d_in[0];
    const int*  src = (const int*)d_in[1];
    const int*  dst = (const int*)d_in[2];
    const float* W1 = (const float*)d_in[3];   // [384][128]
    const float* b1 = (const float*)d_in[4];
    const float* W2 = (const float*)d_in[5];   // [384][64]
    const float* b2 = (const float*)d_in[6];
    float* out = (float*)d_out;
    const int E  = in_sizes[1] / R;
    const int RE = in_sizes[1];
    const int nb = (RE + CHUNK - 1) / CHUNK;      // 293 edge chunks
    const int L  = 2 * NBKT * nb;                 // ~86k
    const int nb1 = (L + 1023) / 1024;            // ~85

    char* ws = (char*)d_ws;
    size_t off = 0;
    auto alloc = [&](size_t bytes) -> void* {
        void* p = ws + off;
        off += (bytes + 255) & ~(size_t)255;
        return p;
    };
    float* bsum1    = (float*)alloc(HID * 4);
    float* bsum2    = (float*)alloc(OUT * 4);
    float* rs_in    = (float*)alloc((size_t)M * 4);
    float* rs_out   = (float*)alloc((size_t)M * 4);
    int*   row_ptr  = (int*)alloc((size_t)(M + 1) * 4);
    int*   bh       = (int*)alloc((size_t)L * 4);
    int*   scanv    = (int*)alloc((size_t)L * 4);
    int*   partials = (int*)alloc((size_t)nb1 * 4);
    unsigned* esrc  = (unsigned*)alloc((size_t)RE * 4);
    __half* F1      = (__half*)alloc((size_t)4 * KB * 64 * 8 * 2);
    __half* F2      = (__half*)alloc((size_t)2 * KB * 64 * 8 * 2);
    // region A: ebd(9.6MB)+ebs(4.8MB) during build; Zagg (38.4MB) for both
    // layers' gathered matrices (L1's dead after gemm1, L2 rewrites it).
    char*  regA     = (char*)alloc((size_t)N * 384 * 2);
    int*   ebd      = (int*)regA;
    unsigned short* ebs = (unsigned short*)(regA + (size_t)RE * 4);
    __half* Z16     = (__half*)regA;
    __half* x16     = (__half*)alloc((size_t)N * IN * 2);   // panel-major [4][N][32]
    __half* H16p    = (__half*)alloc((size_t)N * HID * 2);  // panel-major [4][N][32]

    prep_kernel<<<1 + WPK_B + (CVT_N4 + 255) / 256, 256, 0, stream>>>(
        x, W1, W2, b1, b2, x16, F1, F2, bsum1, bsum2);
    p1_kernel<<<nb, 256, 0, stream>>>(src, dst, E, RE, nb, bh);
    scan1_kernel<<<nb1, 1024, 0, stream>>>(bh, scanv, partials, L);
    scan2_kernel<<<1, 256, 0, stream>>>(partials, nb1);
    p3_kernel<<<nb, 256, 0, stream>>>(src, dst, E, RE, nb, scanv, partials, ebd, ebs);
    pbs_kernel<<<NBKT, 1024, 0, stream>>>(scanv, partials, nb, RE, ebs, rs_out);
    pbd_kernel<<<NBKT, 1024, 0, stream>>>(scanv, partials, nb, RE, ebd, rs_out,
                                          row_ptr, rs_in, esrc);

    const int gb  = N / 16;                   // 3125 gather blocks per pass
    const int ggb = (N + 127) / 128;          // 391 gemm blocks

    // layer 1: Zagg1 = phased-gather(x16); H16p = fp16(relu(bsum1 + Zagg1 @ W1))
    for (int q = 0; q < NPASS; q++)
        gather_kernel<<<gb, 256, 0, stream>>>(x16 + (size_t)q * N * QC, rs_in,
                                              rs_out, row_ptr, esrc,
                                              Z16 + (size_t)q * QC);
    mfma_gemm1_kernel<<<ggb, 256, 0, stream>>>(Z16, F1, bsum1, H16p);
    // layer 2: Zagg2 = phased-gather(H16p); out = bsum2 + Zagg2 @ W2
    for (int q = 0; q < NPASS; q++)
        gather_kernel<<<gb, 256, 0, stream>>>(H16p + (size_t)q * N * QC, rs_in,
                                              rs_out, row_ptr, esrc,
                                              Z16 + (size_t)q * QC);
    mfma_gemm2_kernel<<<ggb, 256, 0, stream>>>(Z16, F2, bsum2, out);
}

// Round 5
// 397.203 us; speedup vs baseline: 1.0841x; 1.0841x over previous
//
#include <hip/hip_runtime.h>
#include <hip/hip_fp16.h>

// RGCN: out = hetero(relu(hetero(x, W1,b1)), W2,b2)
// Layer 1 (IN=HID=128): fused 3-relation gather of x16 -> Z(Nx384), then
//   H16 = fp16(relu(bsum1 + Z @ W1)) via MFMA (W in B-frag layout).
// Layer 2 (OUT=64 < HID): GEMM-FIRST — Y2_r = H16 @ W2_r (fp16, 3x Nx64),
//   then gather_out sums coeff*Y2_r rows (128B/edge) + bias -> fp32 out.
// R13-R15 lesson (reverted): column-phased gathers cut FETCH to compulsory
//   but NEVER cut time — gathers are issue/latency-bound, not fetch-bound;
//   passes multiply per-edge overhead. R16 instead: (a) FUSE the 3 relations'
//   first 16-edge windows so ~24 row loads/lane are in flight on the typical
//   deg~16 row (was 8, serialized per relation); (b) nontemporal esrc loads +
//   Z16 stores keep the 48MB of streams from evicting the x16/Y2 hot sets.
// BK=1024 CSR build: radix partition, zero global atomics.

constexpr int N   = 50000;
constexpr int R   = 3;
constexpr int IN  = 128;
constexpr int HID = 128;
constexpr int OUT = 64;
constexpr int M   = R * N;
constexpr int BK  = 1024;
constexpr int NBKT = (M + BK - 1) / BK;    // 147
constexpr int CHUNK = 8192;
constexpr int KB  = 24;                    // 384/16 k-blocks for MFMA
constexpr int CVT_N4 = N * IN / 4;         // 1.6M float4 groups
constexpr int WPK   = 6 * KB * 64;         // 9216 weight frags
constexpr int WPK_B = (WPK + 255) / 256;   // 36 blocks

typedef _Float16 half8 __attribute__((ext_vector_type(8)));
typedef float floatx16 __attribute__((ext_vector_type(16)));

// ---- prep: bsum (block 0) + wpack (blocks 1..36) + x fp32->fp16 (rest) ----
__global__ void prep_kernel(const float* __restrict__ x,
                            const float* __restrict__ W1, const float* __restrict__ W2,
                            const float* __restrict__ b1, const float* __restrict__ b2,
                            uint2* __restrict__ x16,
                            __half* __restrict__ F1, __half* __restrict__ F2,
                            float* __restrict__ bsum1, float* __restrict__ bsum2) {
    int b = blockIdx.x;
    if (b == 0) {
        int t = threadIdx.x;
        if (t < HID) bsum1[t] = b1[t] + b1[HID + t] + b1[2 * HID + t];
        if (t < OUT) bsum2[t] = b2[t] + b2[OUT + t] + b2[2 * OUT + t];
        return;
    }
    if (b <= WPK_B) {
        int idx = (b - 1) * 256 + threadIdx.x;
        if (idx < 4 * KB * 64) {
            int nt = idx / (KB * 64), rem = idx % (KB * 64);
            int kb = rem / 64, lane = rem % 64;
            int c = nt * 32 + (lane & 31);
            int k0 = kb * 16 + (lane >> 5) * 8;
            __half h[8];
#pragma unroll
            for (int j = 0; j < 8; j++) h[j] = __float2half_rn(W1[(k0 + j) * 128 + c]);
            *(uint4*)(F1 + (size_t)idx * 8) = *(uint4*)h;
        } else if (idx < 6 * KB * 64) {
            int i2 = idx - 4 * KB * 64;
            int nt = i2 / (KB * 64), rem = i2 % (KB * 64);
            int kb = rem / 64, lane = rem % 64;
            int c = nt * 32 + (lane & 31);
            int k0 = kb * 16 + (lane >> 5) * 8;
            __half h[8];
#pragma unroll
            for (int j = 0; j < 8; j++) h[j] = __float2half_rn(W2[(k0 + j) * 64 + c]);
            *(uint4*)(F2 + (size_t)i2 * 8) = *(uint4*)h;
        }
        return;
    }
    int i = (b - 1 - WPK_B) * 256 + threadIdx.x;
    if (i >= CVT_N4) return;
    float4 v = ((const float4*)x)[i];
    __half2 a = __floats2half2_rn(v.x, v.y);
    __half2 c = __floats2half2_rn(v.z, v.w);
    uint2 o;
    o.x = *(unsigned*)&a;
    o.y = *(unsigned*)&c;
    x16[i] = o;
}

// ---- P1: coarse bucket histograms per edge-chunk ----
__global__ __launch_bounds__(256) void p1_kernel(const int* __restrict__ src,
                                                 const int* __restrict__ dst,
                                                 int E, int RE, int nb,
                                                 int* __restrict__ bh) {
    __shared__ int hd[NBKT], hs[NBKT];
    for (int i = threadIdx.x; i < NBKT; i += 256) { hd[i] = 0; hs[i] = 0; }
    __syncthreads();
    int beg = blockIdx.x * CHUNK, end = min(RE, beg + CHUNK);
    for (int g = beg + (int)threadIdx.x; g < end; g += 256) {
        int rb = ((g >= E) + (g >= 2 * E)) * N;
        atomicAdd(&hd[(rb + dst[g]) >> 10], 1);
        atomicAdd(&hs[(rb + src[g]) >> 10], 1);
    }
    __syncthreads();
    for (int i = threadIdx.x; i < NBKT; i += 256) {
        bh[i * nb + blockIdx.x] = hd[i];
        bh[(NBKT + i) * nb + blockIdx.x] = hs[i];
    }
}

// ---- 2-stage exclusive scan (stage-3 folded into consumers) ----
__global__ void scan1_kernel(const int* __restrict__ in, int* __restrict__ out,
                             int* __restrict__ partials, int L) {
    __shared__ int lds[1024];
    int t = threadIdx.x;
    int idx = blockIdx.x * 1024 + t;
    int v = (idx < L) ? in[idx] : 0;
    lds[t] = v;
    __syncthreads();
    for (int off = 1; off < 1024; off <<= 1) {
        int u = (t >= off) ? lds[t - off] : 0;
        __syncthreads();
        lds[t] += u;
        __syncthreads();
    }
    if (idx < L) out[idx] = lds[t] - v;
    if (t == 1023) partials[blockIdx.x] = lds[1023];
}

__global__ void scan2_kernel(int* __restrict__ partials, int nb1) {
    __shared__ int lds[256];
    int t = threadIdx.x;
    int v = (t < nb1) ? partials[t] : 0;
    lds[t] = v;
    __syncthreads();
    for (int off = 1; off < 256; off <<= 1) {
        int u = (t >= off) ? lds[t - off] : 0;
        __syncthreads();
        lds[t] += u;
        __syncthreads();
    }
    if (t < nb1) partials[t] = lds[t] - v;
}

// ---- P3: scatter edges into bucket-sorted buffers via LDS cursors ----
// ebd[pos] = (src<<10)|(dkey&1023); ebs[pos] = skey&1023 (ushort)
__global__ __launch_bounds__(256) void p3_kernel(const int* __restrict__ src,
                                                 const int* __restrict__ dst,
                                                 int E, int RE, int nb,
                                                 const int* __restrict__ scanv,
                                                 const int* __restrict__ partials,
                                                 int* __restrict__ ebd,
                                                 unsigned short* __restrict__ ebs) {
    __shared__ int cd[NBKT], cs[NBKT];
    for (int i = threadIdx.x; i < NBKT; i += 256) {
        int id = i * nb + blockIdx.x;
        int is = (NBKT + i) * nb + blockIdx.x;
        cd[i] = scanv[id] + partials[id >> 10];
        cs[i] = scanv[is] + partials[is >> 10] - RE;
    }
    __syncthreads();
    int beg = blockIdx.x * CHUNK, end = min(RE, beg + CHUNK);
    for (int g = beg + (int)threadIdx.x; g < end; g += 256) {
        int rb = ((g >= E) + (g >= 2 * E)) * N;
        int s  = src[g];
        int kd = rb + dst[g];
        int pd = atomicAdd(&cd[kd >> 10], 1);
        ebd[pd] = (s << 10) | (kd & 1023);
        int ks = rb + s;
        int ps = atomicAdd(&cs[ks >> 10], 1);
        ebs[ps] = (unsigned short)(ks & 1023);
    }
}

// ---- PB-S: per s-bucket exact histogram -> rs_out ----
__global__ __launch_bounds__(1024) void pbs_kernel(const int* __restrict__ scanv,
                                                   const int* __restrict__ partials,
                                                   int nb, int RE,
                                                   const unsigned short* __restrict__ ebs,
                                                   float* __restrict__ rs_out) {
    __shared__ int cnt[BK];
    int t = threadIdx.x;
    int k = blockIdx.x;
    int i0 = (NBKT + k) * nb;
    int segbeg = scanv[i0] + partials[i0 >> 10] - RE;
    int segend;
    if (k == NBKT - 1) segend = RE;
    else {
        int i1 = i0 + nb;
        segend = scanv[i1] + partials[i1 >> 10] - RE;
    }
    cnt[t] = 0;
    __syncthreads();
    for (int e = segbeg + t; e < segend; e += 1024)
        atomicAdd(&cnt[(int)ebs[e]], 1);
    __syncthreads();
    int slot = k * BK + t;
    if (slot < M) rs_out[slot] = rsqrtf((float)(cnt[t] + 1));
}

// ---- PB-D: per d-bucket histogram -> row_ptr/rs_in, scatter coeff-packed esrc ----
__global__ __launch_bounds__(1024) void pbd_kernel(const int* __restrict__ scanv,
                                                   const int* __restrict__ partials,
                                                   int nb, int RE,
                                                   const int* __restrict__ ebd,
                                                   const float* __restrict__ rs_out,
                                                   int* __restrict__ row_ptr,
                                                   float* __restrict__ rs_in,
                                                   unsigned int* __restrict__ esrc) {
    __shared__ int cnt[BK];
    __shared__ int cur[BK];
    int t = threadIdx.x;
    int k = blockIdx.x;
    int i0 = k * nb;
    int segbeg = scanv[i0] + partials[i0 >> 10];
    int segend;
    if (k == NBKT - 1) segend = RE;
    else {
        int i1 = (k + 1) * nb;
        segend = scanv[i1] + partials[i1 >> 10];
    }
    cnt[t] = 0;
    __syncthreads();
    for (int e = segbeg + t; e < segend; e += 1024)
        atomicAdd(&cnt[ebd[e] & 1023], 1);
    __syncthreads();
    int slot = k * BK + t;
    int c = cnt[t];
    cur[t] = c;
    __syncthreads();
    for (int off = 1; off < 1024; off <<= 1) {
        int u = (t >= off) ? cur[t - off] : 0;
        __syncthreads();
        cur[t] += u;
        __syncthreads();
    }
    int excl = cur[t] - c;
    if (slot < M) {
        row_ptr[slot] = segbeg + excl;
        rs_in[slot] = rsqrtf((float)(c + 1));   // +1 self-loop
    }
    if (k == NBKT - 1 && t == 0) row_ptr[M] = RE;
    __syncthreads();
    cur[t] = segbeg + excl;
    __syncthreads();
    for (int e = segbeg + t; e < segend; e += 1024) {
        int v = ebd[e];
        int key = k * BK + (v & 1023);
        int r = (key >= 2 * N) + (key >= N);
        unsigned s = (unsigned)(v >> 10);
        int pos = atomicAdd(&cur[v & 1023], 1);
        __half h = __float2half_rn(rs_out[r * N + s]);
        esrc[pos] = s | ((unsigned)__half_as_ushort(h) << 16);
    }
}

// ---- layer-1 gather: one wave per node; half-wave (pair) per alternate edge;
// 32 lanes x uint2 = 256B row. FUSED first window: 16 edges x 3 relations
// issued together -> 24 row loads in flight/lane (deg~16 rows previously
// capped at 8). Residual predicated 16-edge windows for deg>16. NT esrc
// loads + NT Z stores (as ull) keep streams out of the x16 L2 hot set. ----
__global__ __launch_bounds__(256) void gather_kernel(const __half* __restrict__ Xh,
                                                     const float* __restrict__ rs_in,
                                                     const float* __restrict__ rs_out,
                                                     const int* __restrict__ row_ptr,
                                                     const unsigned int* __restrict__ esrc,
                                                     __half* __restrict__ Z16) {
    int n = blockIdx.x * 4 + (threadIdx.x >> 6);
    if (n >= N) return;
    int lane = threadIdx.x & 63;
    int pair = lane >> 5;
    int c4 = (lane & 31) * 4;               // 4 cols per lane
    uint2 xn = *(const uint2*)(Xh + (long)n * 128 + c4);
    const __half2 z2 = __float2half2_rn(0.f);
    int beg[R], end[R];
#pragma unroll
    for (int r = 0; r < R; r++) {
        int key = r * N + n;
        beg[r] = row_ptr[key];
        end[r] = row_ptr[key + 1];
    }
    __half2 acc0[R], acc1[R];
#pragma unroll
    for (int r = 0; r < R; r++) { acc0[r] = z2; acc1[r] = z2; }

    // fused first window: indices for all 3 relations, then all 24 row loads
    unsigned u[R][8];
#pragma unroll
    for (int r = 0; r < R; r++)
#pragma unroll
        for (int j = 0; j < 8; j++) {
            int idx = beg[r] + 2 * j + pair;
            u[r][j] = (idx < end[r]) ? __builtin_nontemporal_load(esrc + idx) : 0u;
        }
    uint2 y[R][8];
#pragma unroll
    for (int r = 0; r < R; r++)
#pragma unroll
        for (int j = 0; j < 8; j++)
            y[r][j] = *(const uint2*)(Xh + (long)(u[r][j] & 0xffffu) * 128 + c4);
#pragma unroll
    for (int r = 0; r < R; r++)
#pragma unroll
        for (int j = 0; j < 8; j++) {
            __half2 cj = __half2half2(__ushort_as_half((unsigned short)(u[r][j] >> 16)));
            acc0[r] = __hfma2(*(__half2*)&y[r][j].x, cj, acc0[r]);
            acc1[r] = __hfma2(*(__half2*)&y[r][j].y, cj, acc1[r]);
        }

    // residual windows (deg > 16): predicated 16-edge steps
#pragma unroll
    for (int r = 0; r < R; r++) {
        for (int e = beg[r] + 16; e < end[r]; e += 16) {
            unsigned uu[8];
#pragma unroll
            for (int j = 0; j < 8; j++) {
                int idx = e + 2 * j + pair;
                uu[j] = (idx < end[r]) ? __builtin_nontemporal_load(esrc + idx) : 0u;
            }
            uint2 yy[8];
#pragma unroll
            for (int j = 0; j < 8; j++)
                yy[j] = *(const uint2*)(Xh + (long)(uu[j] & 0xffffu) * 128 + c4);
#pragma unroll
            for (int j = 0; j < 8; j++) {
                __half2 cj = __half2half2(__ushort_as_half((unsigned short)(uu[j] >> 16)));
                acc0[r] = __hfma2(*(__half2*)&yy[j].x, cj, acc0[r]);
                acc1[r] = __hfma2(*(__half2*)&yy[j].y, cj, acc1[r]);
            }
        }
    }

#pragma unroll
    for (int r = 0; r < R; r++) {
        int key = r * N + n;
        unsigned a0 = *(unsigned*)&acc0[r], a1 = *(unsigned*)&acc1[r];
        unsigned b0 = (unsigned)__shfl_xor((int)a0, 32, 64);
        unsigned b1 = (unsigned)__shfl_xor((int)a1, 32, 64);
        __half2 s0 = __hadd2(acc0[r], *(__half2*)&b0);
        __half2 s1 = __hadd2(acc1[r], *(__half2*)&b1);
        __half2 cs = __float2half2_rn(rs_out[key]);
        s0 = __hfma2(*(__half2*)&xn.x, cs, s0);
        s1 = __hfma2(*(__half2*)&xn.y, cs, s1);
        __half2 ri = __float2half2_rn(rs_in[key]);
        s0 = __hmul2(s0, ri);
        s1 = __hmul2(s1, ri);
        if (pair == 0) {
            unsigned lo = *(unsigned*)&s0;
            unsigned hi = *(unsigned*)&s1;
            unsigned long long o = ((unsigned long long)hi << 32) | lo;
            __builtin_nontemporal_store(
                o, (unsigned long long*)(Z16 + (long)n * 384 + r * 128 + c4));
        }
    }
}

// ---- layer-1 MFMA GEMM: H16 = fp16(relu(bias + Z16[N,384] @ W1)); A-frags
// direct from Z16 rows, B-frags from F1. 32x32x16 f16.
// C/D map: col=lane&31, row=(reg&3)+8*(reg>>2)+4*(lane>>5)  [m74/m101 verified]
__global__ __launch_bounds__(256) void mfma_gemm1_kernel(const __half* __restrict__ Z16,
                                                         const __half* __restrict__ F,
                                                         const float* __restrict__ bias,
                                                         __half* __restrict__ H16) {
    int wave = threadIdx.x >> 6, lane = threadIdx.x & 63;
    int m0 = blockIdx.x * 128 + wave * 32;
    int mr = min(m0 + (lane & 31), N - 1);
    const half8* A = (const half8*)(Z16 + (long)mr * 384 + (lane >> 5) * 8);
    const half8* B = (const half8*)F;
    floatx16 acc[4];
#pragma unroll
    for (int i = 0; i < 4; i++)
#pragma unroll
        for (int j = 0; j < 16; j++) acc[i][j] = 0.f;

    half8 a = A[0];
    for (int kb = 0; kb < KB; kb++) {
        half8 an = (kb < KB - 1) ? A[(kb + 1) * 2] : a;
#pragma unroll
        for (int nt = 0; nt < 4; nt++) {
            half8 b = B[(nt * KB + kb) * 64 + lane];
            acc[nt] = __builtin_amdgcn_mfma_f32_32x32x16_f16(a, b, acc[nt], 0, 0, 0);
        }
        a = an;
    }
    float bv[4];
#pragma unroll
    for (int nt = 0; nt < 4; nt++) bv[nt] = bias[nt * 32 + (lane & 31)];
    int rbase = m0 + 4 * (lane >> 5);
    int col0 = lane & 31;
#pragma unroll
    for (int nt = 0; nt < 4; nt++) {
#pragma unroll
        for (int reg = 0; reg < 16; reg++) {
            int row = rbase + (reg & 3) + 8 * (reg >> 2);
            if (row < N) {
                float v = fmaxf(acc[nt][reg] + bv[nt], 0.f);
                H16[(long)row * 128 + nt * 32 + col0] = __float2half_rn(v);
            }
        }
    }
}

// ---- layer-2 GEMM-first: Y2[r][N][64] = H16[N,128] @ W2_r (fp16 out, no bias).
// F2 kb-layout: relation r's K-chunk is kb = r*8 + kbr. blockIdx.y = r. ----
__global__ __launch_bounds__(256) void mfma_gemmY_kernel(const __half* __restrict__ H16,
                                                         const __half* __restrict__ F,
                                                         __half* __restrict__ Y2) {
    int wave = threadIdx.x >> 6, lane = threadIdx.x & 63;
    int r = blockIdx.y;
    int m0 = blockIdx.x * 128 + wave * 32;
    int mr = min(m0 + (lane & 31), N - 1);
    const half8* A = (const half8*)(H16 + (long)mr * 128 + (lane >> 5) * 8);
    const half8* B = (const half8*)F;
    floatx16 acc[2];
#pragma unroll
    for (int i = 0; i < 2; i++)
#pragma unroll
        for (int j = 0; j < 16; j++) acc[i][j] = 0.f;

#pragma unroll
    for (int kbr = 0; kbr < 8; kbr++) {
        half8 a = A[kbr * 2];
#pragma unroll
        for (int nt = 0; nt < 2; nt++) {
            half8 b = B[(nt * KB + r * 8 + kbr) * 64 + lane];
            acc[nt] = __builtin_amdgcn_mfma_f32_32x32x16_f16(a, b, acc[nt], 0, 0, 0);
        }
    }
    int rbase = m0 + 4 * (lane >> 5);
    int col0 = lane & 31;
    __half* Yr = Y2 + (long)r * N * 64;
#pragma unroll
    for (int nt = 0; nt < 2; nt++) {
#pragma unroll
        for (int reg = 0; reg < 16; reg++) {
            int row = rbase + (reg & 3) + 8 * (reg >> 2);
            if (row < N)
                Yr[(long)row * 64 + nt * 32 + col0] = __float2half_rn(acc[nt][reg]);
        }
    }
}

// ---- layer-2 gather: out[n] = bsum2 + sum_r rs_in*(sum_e coeff*Y2_r[s] + rs_out*Y2_r[n]).
// 128B rows: 32 lanes x half2 (dword); pair = lane>>5 handles alternate edges.
// FUSED first window across the 3 relations (24 dword loads in flight/lane),
// predicated residual windows, NT esrc loads. fp32 out. ----
__global__ __launch_bounds__(256) void gather_out_kernel(const __half* __restrict__ Y2,
                                                         const float* __restrict__ rs_in,
                                                         const float* __restrict__ rs_out,
                                                         const int* __restrict__ row_ptr,
                                                         const unsigned int* __restrict__ esrc,
                                                         const float* __restrict__ bias,
                                                         float* __restrict__ outp) {
    int n = blockIdx.x * 4 + (threadIdx.x >> 6);
    if (n >= N) return;
    int lane = threadIdx.x & 63;
    int pair = lane >> 5;
    int c2 = (lane & 31) * 2;               // 2 cols per lane
    const __half2 z2 = __float2half2_rn(0.f);
    float2 tot = ((const float2*)bias)[lane & 31];
    int beg[R], end[R];
#pragma unroll
    for (int r = 0; r < R; r++) {
        int key = r * N + n;
        beg[r] = row_ptr[key];
        end[r] = row_ptr[key + 1];
    }
    __half2 acc[R];
#pragma unroll
    for (int r = 0; r < R; r++) acc[r] = z2;

    // fused first window
    unsigned u[R][8];
#pragma unroll
    for (int r = 0; r < R; r++)
#pragma unroll
        for (int j = 0; j < 8; j++) {
            int idx = beg[r] + 2 * j + pair;
            u[r][j] = (idx < end[r]) ? __builtin_nontemporal_load(esrc + idx) : 0u;
        }
    __half2 y[R][8];
#pragma unroll
    for (int r = 0; r < R; r++)
#pragma unroll
        for (int j = 0; j < 8; j++)
            y[r][j] = *(const __half2*)(Y2 + (long)r * N * 64 +
                                        (long)(u[r][j] & 0xffffu) * 64 + c2);
#pragma unroll
    for (int r = 0; r < R; r++)
#pragma unroll
        for (int j = 0; j < 8; j++)
            acc[r] = __hfma2(y[r][j],
                             __half2half2(__ushort_as_half((unsigned short)(u[r][j] >> 16))),
                             acc[r]);

    // residual windows (deg > 16)
#pragma unroll
    for (int r = 0; r < R; r++) {
        const __half* Yr = Y2 + (long)r * N * 64;
        for (int e = beg[r] + 16; e < end[r]; e += 16) {
            unsigned uu[8];
#pragma unroll
            for (int j = 0; j < 8; j++) {
                int idx = e + 2 * j + pair;
                uu[j] = (idx < end[r]) ? __builtin_nontemporal_load(esrc + idx) : 0u;
            }
            __half2 yy[8];
#pragma unroll
            for (int j = 0; j < 8; j++)
                yy[j] = *(const __half2*)(Yr + (long)(uu[j] & 0xffffu) * 64 + c2);
#pragma unroll
            for (int j = 0; j < 8; j++)
                acc[r] = __hfma2(yy[j],
                                 __half2half2(__ushort_as_half((unsigned short)(uu[j] >> 16))),
                                 acc[r]);
        }
    }

#pragma unroll
    for (int r = 0; r < R; r++) {
        int key = r * N + n;
        const __half* Yr = Y2 + (long)r * N * 64;
        unsigned a0 = *(unsigned*)&acc[r];
        unsigned b0 = (unsigned)__shfl_xor((int)a0, 32, 64);
        __half2 s = __hadd2(acc[r], *(__half2*)&b0);
        // self-loop
        __half2 ys = *(const __half2*)(Yr + (long)n * 64 + c2);
        s = __hfma2(ys, __float2half2_rn(rs_out[key]), s);
        float2 f = __half22float2(s);
        float ri = rs_in[key];
        tot.x += ri * f.x;
        tot.y += ri * f.y;
    }
    if (pair == 0) *(float2*)(outp + (long)n * 64 + c2) = tot;
}

extern "C" void kernel_launch(void* const* d_in, const int* in_sizes, int n_in,
                              void* d_out, int out_size, void* d_ws, size_t ws_size,
                              hipStream_t stream) {
    const float* x  = (const float*)d_in[0];
    const int*  src = (const int*)d_in[1];
    const int*  dst = (const int*)d_in[2];
    const float* W1 = (const float*)d_in[3];   // [384][128]
    const float* b1 = (const float*)d_in[4];
    const float* W2 = (const float*)d_in[5];   // [384][64]
    const float* b2 = (const float*)d_in[6];
    float* out = (float*)d_out;
    const int E  = in_sizes[1] / R;
    const int RE = in_sizes[1];
    const int nb = (RE + CHUNK - 1) / CHUNK;      // 293 edge chunks
    const int L  = 2 * NBKT * nb;                 // ~86k
    const int nb1 = (L + 1023) / 1024;            // ~85

    char* ws = (char*)d_ws;
    size_t off = 0;
    auto alloc = [&](size_t bytes) -> void* {
        void* p = ws + off;
        off += (bytes + 255) & ~(size_t)255;
        return p;
    };
    float* bsum1    = (float*)alloc(HID * 4);
    float* bsum2    = (float*)alloc(OUT * 4);
    float* rs_in    = (float*)alloc((size_t)M * 4);
    float* rs_out   = (float*)alloc((size_t)M * 4);
    int*   row_ptr  = (int*)alloc((size_t)(M + 1) * 4);
    int*   bh       = (int*)alloc((size_t)L * 4);
    int*   scanv    = (int*)alloc((size_t)L * 4);
    int*   partials = (int*)alloc((size_t)nb1 * 4);
    unsigned* esrc  = (unsigned*)alloc((size_t)RE * 4);
    __half* F1      = (__half*)alloc((size_t)4 * KB * 64 * 8 * 2);
    __half* F2      = (__half*)alloc((size_t)2 * KB * 64 * 8 * 2);
    // region A: ebd(9.6MB)+ebs(4.8MB) during build; Z16 (38.4MB) for layer 1;
    // Y2 (19.2MB) for layer 2 (Z16 dead after gemm1).
    char*  regA     = (char*)alloc((size_t)N * 384 * 2);
    int*   ebd      = (int*)regA;
    unsigned short* ebs = (unsigned short*)(regA + (size_t)RE * 4);
    __half* Z16     = (__half*)regA;
    __half* Y2      = (__half*)regA;
    __half* x16     = (__half*)alloc((size_t)N * IN * 2);
    __half* H16     = (__half*)alloc((size_t)N * HID * 2);

    prep_kernel<<<1 + WPK_B + (CVT_N4 + 255) / 256, 256, 0, stream>>>(
        x, W1, W2, b1, b2, (uint2*)x16, F1, F2, bsum1, bsum2);
    p1_kernel<<<nb, 256, 0, stream>>>(src, dst, E, RE, nb, bh);
    scan1_kernel<<<nb1, 1024, 0, stream>>>(bh, scanv, partials, L);
    scan2_kernel<<<1, 256, 0, stream>>>(partials, nb1);
    p3_kernel<<<nb, 256, 0, stream>>>(src, dst, E, RE, nb, scanv, partials, ebd, ebs);
    pbs_kernel<<<NBKT, 1024, 0, stream>>>(scanv, partials, nb, RE, ebs, rs_out);
    pbd_kernel<<<NBKT, 1024, 0, stream>>>(scanv, partials, nb, RE, ebd, rs_out,
                                          row_ptr, rs_in, esrc);

    const int ab  = (N + 3) / 4;              // 12500 gather blocks
    const int ggb = (N + 127) / 128;          // 391 gemm blocks

    // layer 1: Z = gather(x16); H16 = fp16(relu(bsum1 + Z @ W1))
    gather_kernel<<<ab, 256, 0, stream>>>(x16, rs_in, rs_out, row_ptr, esrc, Z16);
    mfma_gemm1_kernel<<<ggb, 256, 0, stream>>>(Z16, F1, bsum1, H16);
    // layer 2 (GEMM-first): Y2_r = H16 @ W2_r; out = bsum2 + agg(Y2)
    mfma_gemmY_kernel<<<dim3(ggb, R), 256, 0, stream>>>(H16, F2, Y2);
    gather_out_kernel<<<ab, 256, 0, stream>>>(Y2, rs_in, rs_out, row_ptr, esrc,
                                              bsum2, out);
}

// Round 6
// 347.602 us; speedup vs baseline: 1.2388x; 1.1427x over previous
//
#include <hip/hip_runtime.h>
#include <hip/hip_fp16.h>

// RGCN: out = hetero(relu(hetero(x, W1,b1)), W2,b2)
// Layer 1 (IN=HID=128): fused 3-relation gather of x16 -> Z(Nx384), then
//   H16 = fp16(relu(bsum1 + Z @ W1)) via MFMA (W in B-frag layout).
// Layer 2 (OUT=64 < HID): GEMM-FIRST — Y2_r = H16 @ W2_r (fp16, 3x Nx64),
//   then gather_out sums coeff*Y2_r rows + bias -> fp32 out.
// Gather arc: R13-R15 column-phasing cut FETCH to compulsory but never cut
//   time (latency-bound, not fetch-bound). R16 relation-fusion raised MLP but
//   crashed occupancy (48 VGPR of in-flight rows). R17: QUARTER-WAVE PER EDGE
//   (16 lanes x uint4 = 256B row) -> 4 edges/instr; ONE uniform predicated
//   24-edge window (no serial 2-edge tails; pred-out lanes hit L1-hot row 0
//   with coeff +0); 2-step shfl reduce. More outstanding lines/wave at ~52
//   VGPR, 8 waves/SIMD kept.
// BK=1024 CSR build: radix partition, zero global atomics.

constexpr int N   = 50000;
constexpr int R   = 3;
constexpr int IN  = 128;
constexpr int HID = 128;
constexpr int OUT = 64;
constexpr int M   = R * N;
constexpr int BK  = 1024;
constexpr int NBKT = (M + BK - 1) / BK;    // 147
constexpr int CHUNK = 8192;
constexpr int KB  = 24;                    // 384/16 k-blocks for MFMA
constexpr int CVT_N4 = N * IN / 4;         // 1.6M float4 groups
constexpr int WPK   = 6 * KB * 64;         // 9216 weight frags
constexpr int WPK_B = (WPK + 255) / 256;   // 36 blocks

typedef _Float16 half8 __attribute__((ext_vector_type(8)));
typedef float floatx16 __attribute__((ext_vector_type(16)));

// ---- prep: bsum (block 0) + wpack (blocks 1..36) + x fp32->fp16 (rest) ----
__global__ void prep_kernel(const float* __restrict__ x,
                            const float* __restrict__ W1, const float* __restrict__ W2,
                            const float* __restrict__ b1, const float* __restrict__ b2,
                            uint2* __restrict__ x16,
                            __half* __restrict__ F1, __half* __restrict__ F2,
                            float* __restrict__ bsum1, float* __restrict__ bsum2) {
    int b = blockIdx.x;
    if (b == 0) {
        int t = threadIdx.x;
        if (t < HID) bsum1[t] = b1[t] + b1[HID + t] + b1[2 * HID + t];
        if (t < OUT) bsum2[t] = b2[t] + b2[OUT + t] + b2[2 * OUT + t];
        return;
    }
    if (b <= WPK_B) {
        int idx = (b - 1) * 256 + threadIdx.x;
        if (idx < 4 * KB * 64) {
            int nt = idx / (KB * 64), rem = idx % (KB * 64);
            int kb = rem / 64, lane = rem % 64;
            int c = nt * 32 + (lane & 31);
            int k0 = kb * 16 + (lane >> 5) * 8;
            __half h[8];
#pragma unroll
            for (int j = 0; j < 8; j++) h[j] = __float2half_rn(W1[(k0 + j) * 128 + c]);
            *(uint4*)(F1 + (size_t)idx * 8) = *(uint4*)h;
        } else if (idx < 6 * KB * 64) {
            int i2 = idx - 4 * KB * 64;
            int nt = i2 / (KB * 64), rem = i2 % (KB * 64);
            int kb = rem / 64, lane = rem % 64;
            int c = nt * 32 + (lane & 31);
            int k0 = kb * 16 + (lane >> 5) * 8;
            __half h[8];
#pragma unroll
            for (int j = 0; j < 8; j++) h[j] = __float2half_rn(W2[(k0 + j) * 64 + c]);
            *(uint4*)(F2 + (size_t)i2 * 8) = *(uint4*)h;
        }
        return;
    }
    int i = (b - 1 - WPK_B) * 256 + threadIdx.x;
    if (i >= CVT_N4) return;
    float4 v = ((const float4*)x)[i];
    __half2 a = __floats2half2_rn(v.x, v.y);
    __half2 c = __floats2half2_rn(v.z, v.w);
    uint2 o;
    o.x = *(unsigned*)&a;
    o.y = *(unsigned*)&c;
    x16[i] = o;
}

// ---- P1: coarse bucket histograms per edge-chunk ----
__global__ __launch_bounds__(256) void p1_kernel(const int* __restrict__ src,
                                                 const int* __restrict__ dst,
                                                 int E, int RE, int nb,
                                                 int* __restrict__ bh) {
    __shared__ int hd[NBKT], hs[NBKT];
    for (int i = threadIdx.x; i < NBKT; i += 256) { hd[i] = 0; hs[i] = 0; }
    __syncthreads();
    int beg = blockIdx.x * CHUNK, end = min(RE, beg + CHUNK);
    for (int g = beg + (int)threadIdx.x; g < end; g += 256) {
        int rb = ((g >= E) + (g >= 2 * E)) * N;
        atomicAdd(&hd[(rb + dst[g]) >> 10], 1);
        atomicAdd(&hs[(rb + src[g]) >> 10], 1);
    }
    __syncthreads();
    for (int i = threadIdx.x; i < NBKT; i += 256) {
        bh[i * nb + blockIdx.x] = hd[i];
        bh[(NBKT + i) * nb + blockIdx.x] = hs[i];
    }
}

// ---- 2-stage exclusive scan (stage-3 folded into consumers) ----
__global__ void scan1_kernel(const int* __restrict__ in, int* __restrict__ out,
                             int* __restrict__ partials, int L) {
    __shared__ int lds[1024];
    int t = threadIdx.x;
    int idx = blockIdx.x * 1024 + t;
    int v = (idx < L) ? in[idx] : 0;
    lds[t] = v;
    __syncthreads();
    for (int off = 1; off < 1024; off <<= 1) {
        int u = (t >= off) ? lds[t - off] : 0;
        __syncthreads();
        lds[t] += u;
        __syncthreads();
    }
    if (idx < L) out[idx] = lds[t] - v;
    if (t == 1023) partials[blockIdx.x] = lds[1023];
}

__global__ void scan2_kernel(int* __restrict__ partials, int nb1) {
    __shared__ int lds[256];
    int t = threadIdx.x;
    int v = (t < nb1) ? partials[t] : 0;
    lds[t] = v;
    __syncthreads();
    for (int off = 1; off < 256; off <<= 1) {
        int u = (t >= off) ? lds[t - off] : 0;
        __syncthreads();
        lds[t] += u;
        __syncthreads();
    }
    if (t < nb1) partials[t] = lds[t] - v;
}

// ---- P3: scatter edges into bucket-sorted buffers via LDS cursors ----
// ebd[pos] = (src<<10)|(dkey&1023); ebs[pos] = skey&1023 (ushort)
__global__ __launch_bounds__(256) void p3_kernel(const int* __restrict__ src,
                                                 const int* __restrict__ dst,
                                                 int E, int RE, int nb,
                                                 const int* __restrict__ scanv,
                                                 const int* __restrict__ partials,
                                                 int* __restrict__ ebd,
                                                 unsigned short* __restrict__ ebs) {
    __shared__ int cd[NBKT], cs[NBKT];
    for (int i = threadIdx.x; i < NBKT; i += 256) {
        int id = i * nb + blockIdx.x;
        int is = (NBKT + i) * nb + blockIdx.x;
        cd[i] = scanv[id] + partials[id >> 10];
        cs[i] = scanv[is] + partials[is >> 10] - RE;
    }
    __syncthreads();
    int beg = blockIdx.x * CHUNK, end = min(RE, beg + CHUNK);
    for (int g = beg + (int)threadIdx.x; g < end; g += 256) {
        int rb = ((g >= E) + (g >= 2 * E)) * N;
        int s  = src[g];
        int kd = rb + dst[g];
        int pd = atomicAdd(&cd[kd >> 10], 1);
        ebd[pd] = (s << 10) | (kd & 1023);
        int ks = rb + s;
        int ps = atomicAdd(&cs[ks >> 10], 1);
        ebs[ps] = (unsigned short)(ks & 1023);
    }
}

// ---- PB-S: per s-bucket exact histogram -> rs_out ----
__global__ __launch_bounds__(1024) void pbs_kernel(const int* __restrict__ scanv,
                                                   const int* __restrict__ partials,
                                                   int nb, int RE,
                                                   const unsigned short* __restrict__ ebs,
                                                   float* __restrict__ rs_out) {
    __shared__ int cnt[BK];
    int t = threadIdx.x;
    int k = blockIdx.x;
    int i0 = (NBKT + k) * nb;
    int segbeg = scanv[i0] + partials[i0 >> 10] - RE;
    int segend;
    if (k == NBKT - 1) segend = RE;
    else {
        int i1 = i0 + nb;
        segend = scanv[i1] + partials[i1 >> 10] - RE;
    }
    cnt[t] = 0;
    __syncthreads();
    for (int e = segbeg + t; e < segend; e += 1024)
        atomicAdd(&cnt[(int)ebs[e]], 1);
    __syncthreads();
    int slot = k * BK + t;
    if (slot < M) rs_out[slot] = rsqrtf((float)(cnt[t] + 1));
}

// ---- PB-D: per d-bucket histogram -> row_ptr/rs_in, scatter coeff-packed esrc ----
__global__ __launch_bounds__(1024) void pbd_kernel(const int* __restrict__ scanv,
                                                   const int* __restrict__ partials,
                                                   int nb, int RE,
                                                   const int* __restrict__ ebd,
                                                   const float* __restrict__ rs_out,
                                                   int* __restrict__ row_ptr,
                                                   float* __restrict__ rs_in,
                                                   unsigned int* __restrict__ esrc) {
    __shared__ int cnt[BK];
    __shared__ int cur[BK];
    int t = threadIdx.x;
    int k = blockIdx.x;
    int i0 = k * nb;
    int segbeg = scanv[i0] + partials[i0 >> 10];
    int segend;
    if (k == NBKT - 1) segend = RE;
    else {
        int i1 = (k + 1) * nb;
        segend = scanv[i1] + partials[i1 >> 10];
    }
    cnt[t] = 0;
    __syncthreads();
    for (int e = segbeg + t; e < segend; e += 1024)
        atomicAdd(&cnt[ebd[e] & 1023], 1);
    __syncthreads();
    int slot = k * BK + t;
    int c = cnt[t];
    cur[t] = c;
    __syncthreads();
    for (int off = 1; off < 1024; off <<= 1) {
        int u = (t >= off) ? cur[t - off] : 0;
        __syncthreads();
        cur[t] += u;
        __syncthreads();
    }
    int excl = cur[t] - c;
    if (slot < M) {
        row_ptr[slot] = segbeg + excl;
        rs_in[slot] = rsqrtf((float)(c + 1));   // +1 self-loop
    }
    if (k == NBKT - 1 && t == 0) row_ptr[M] = RE;
    __syncthreads();
    cur[t] = segbeg + excl;
    __syncthreads();
    for (int e = segbeg + t; e < segend; e += 1024) {
        int v = ebd[e];
        int key = k * BK + (v & 1023);
        int r = (key >= 2 * N) + (key >= N);
        unsigned s = (unsigned)(v >> 10);
        int pos = atomicAdd(&cur[v & 1023], 1);
        __half h = __float2half_rn(rs_out[r * N + s]);
        esrc[pos] = s | ((unsigned)__half_as_ushort(h) << 16);
    }
}

// ---- layer-1 gather: one wave per node; QUARTER-WAVE (16 lanes) per edge,
// uint4/lane = full 256B row per group -> 4 edges per load instruction.
// One uniform predicated 24-edge window (6 loads in flight/lane); pred-out
// lanes load row 0 (L1-hot) with coeff +0. 2-step shfl_xor(16,32) reduce.
// Lanes 0-15 store the 256B Z row. ----
__global__ __launch_bounds__(256) void gather_kernel(const __half* __restrict__ Xh,
                                                     const float* __restrict__ rs_in,
                                                     const float* __restrict__ rs_out,
                                                     const int* __restrict__ row_ptr,
                                                     const unsigned int* __restrict__ esrc,
                                                     __half* __restrict__ Z16) {
    int n = blockIdx.x * 4 + (threadIdx.x >> 6);
    if (n >= N) return;
    int lane = threadIdx.x & 63;
    int g = lane >> 4;                       // edge sub-slot 0..3
    int cl = lane & 15;                      // 8 cols: c = cl*8
    const __half* xrow = Xh + (long)n * 128 + cl * 8;
    uint4 xn = *(const uint4*)xrow;
#pragma unroll
    for (int r = 0; r < R; r++) {
        int key = r * N + n;
        int beg = row_ptr[key], end = row_ptr[key + 1];
        __half2 a0 = __float2half2_rn(0.f), a1 = a0, a2 = a0, a3 = a0;
        for (int e = beg; e < end; e += 24) {
            unsigned u[6];
#pragma unroll
            for (int j = 0; j < 6; j++) {
                int idx = e + 4 * j + g;
                u[j] = (idx < end) ? esrc[idx] : 0u;   // coeff bits 0 -> adds 0
            }
            uint4 y[6];
#pragma unroll
            for (int j = 0; j < 6; j++)
                y[j] = *(const uint4*)(Xh + (long)(u[j] & 0xffffu) * 128 + cl * 8);
#pragma unroll
            for (int j = 0; j < 6; j++) {
                __half2 cj = __half2half2(__ushort_as_half((unsigned short)(u[j] >> 16)));
                a0 = __hfma2(*(__half2*)&y[j].x, cj, a0);
                a1 = __hfma2(*(__half2*)&y[j].y, cj, a1);
                a2 = __hfma2(*(__half2*)&y[j].z, cj, a2);
                a3 = __hfma2(*(__half2*)&y[j].w, cj, a3);
            }
        }
        // reduce over the 4 edge sub-slots (lanes l, l^16, l^32, l^48)
#pragma unroll
        for (int off = 16; off < 64; off <<= 1) {
            unsigned w0 = *(unsigned*)&a0, w1 = *(unsigned*)&a1;
            unsigned w2 = *(unsigned*)&a2, w3 = *(unsigned*)&a3;
            unsigned v0 = (unsigned)__shfl_xor((int)w0, off, 64);
            unsigned v1 = (unsigned)__shfl_xor((int)w1, off, 64);
            unsigned v2 = (unsigned)__shfl_xor((int)w2, off, 64);
            unsigned v3 = (unsigned)__shfl_xor((int)w3, off, 64);
            a0 = __hadd2(a0, *(__half2*)&v0);
            a1 = __hadd2(a1, *(__half2*)&v1);
            a2 = __hadd2(a2, *(__half2*)&v2);
            a3 = __hadd2(a3, *(__half2*)&v3);
        }
        __half2 cs = __float2half2_rn(rs_out[key]);
        a0 = __hfma2(*(__half2*)&xn.x, cs, a0);
        a1 = __hfma2(*(__half2*)&xn.y, cs, a1);
        a2 = __hfma2(*(__half2*)&xn.z, cs, a2);
        a3 = __hfma2(*(__half2*)&xn.w, cs, a3);
        __half2 ri = __float2half2_rn(rs_in[key]);
        a0 = __hmul2(a0, ri);
        a1 = __hmul2(a1, ri);
        a2 = __hmul2(a2, ri);
        a3 = __hmul2(a3, ri);
        if (g == 0) {
            uint4 o;
            o.x = *(unsigned*)&a0;
            o.y = *(unsigned*)&a1;
            o.z = *(unsigned*)&a2;
            o.w = *(unsigned*)&a3;
            *(uint4*)(Z16 + (long)n * 384 + r * 128 + cl * 8) = o;
        }
    }
}

// ---- layer-1 MFMA GEMM: H16 = fp16(relu(bias + Z16[N,384] @ W1)); A-frags
// direct from Z16 rows, B-frags from F1. 32x32x16 f16.
// C/D map: col=lane&31, row=(reg&3)+8*(reg>>2)+4*(lane>>5)  [m74/m101 verified]
__global__ __launch_bounds__(256) void mfma_gemm1_kernel(const __half* __restrict__ Z16,
                                                         const __half* __restrict__ F,
                                                         const float* __restrict__ bias,
                                                         __half* __restrict__ H16) {
    int wave = threadIdx.x >> 6, lane = threadIdx.x & 63;
    int m0 = blockIdx.x * 128 + wave * 32;
    int mr = min(m0 + (lane & 31), N - 1);
    const half8* A = (const half8*)(Z16 + (long)mr * 384 + (lane >> 5) * 8);
    const half8* B = (const half8*)F;
    floatx16 acc[4];
#pragma unroll
    for (int i = 0; i < 4; i++)
#pragma unroll
        for (int j = 0; j < 16; j++) acc[i][j] = 0.f;

    half8 a = A[0];
    for (int kb = 0; kb < KB; kb++) {
        half8 an = (kb < KB - 1) ? A[(kb + 1) * 2] : a;
#pragma unroll
        for (int nt = 0; nt < 4; nt++) {
            half8 b = B[(nt * KB + kb) * 64 + lane];
            acc[nt] = __builtin_amdgcn_mfma_f32_32x32x16_f16(a, b, acc[nt], 0, 0, 0);
        }
        a = an;
    }
    float bv[4];
#pragma unroll
    for (int nt = 0; nt < 4; nt++) bv[nt] = bias[nt * 32 + (lane & 31)];
    int rbase = m0 + 4 * (lane >> 5);
    int col0 = lane & 31;
#pragma unroll
    for (int nt = 0; nt < 4; nt++) {
#pragma unroll
        for (int reg = 0; reg < 16; reg++) {
            int row = rbase + (reg & 3) + 8 * (reg >> 2);
            if (row < N) {
                float v = fmaxf(acc[nt][reg] + bv[nt], 0.f);
                H16[(long)row * 128 + nt * 32 + col0] = __float2half_rn(v);
            }
        }
    }
}

// ---- layer-2 GEMM-first: Y2[r][N][64] = H16[N,128] @ W2_r (fp16 out, no bias).
// F2 kb-layout: relation r's K-chunk is kb = r*8 + kbr. blockIdx.y = r. ----
__global__ __launch_bounds__(256) void mfma_gemmY_kernel(const __half* __restrict__ H16,
                                                         const __half* __restrict__ F,
                                                         __half* __restrict__ Y2) {
    int wave = threadIdx.x >> 6, lane = threadIdx.x & 63;
    int r = blockIdx.y;
    int m0 = blockIdx.x * 128 + wave * 32;
    int mr = min(m0 + (lane & 31), N - 1);
    const half8* A = (const half8*)(H16 + (long)mr * 128 + (lane >> 5) * 8);
    const half8* B = (const half8*)F;
    floatx16 acc[2];
#pragma unroll
    for (int i = 0; i < 2; i++)
#pragma unroll
        for (int j = 0; j < 16; j++) acc[i][j] = 0.f;

#pragma unroll
    for (int kbr = 0; kbr < 8; kbr++) {
        half8 a = A[kbr * 2];
#pragma unroll
        for (int nt = 0; nt < 2; nt++) {
            half8 b = B[(nt * KB + r * 8 + kbr) * 64 + lane];
            acc[nt] = __builtin_amdgcn_mfma_f32_32x32x16_f16(a, b, acc[nt], 0, 0, 0);
        }
    }
    int rbase = m0 + 4 * (lane >> 5);
    int col0 = lane & 31;
    __half* Yr = Y2 + (long)r * N * 64;
#pragma unroll
    for (int nt = 0; nt < 2; nt++) {
#pragma unroll
        for (int reg = 0; reg < 16; reg++) {
            int row = rbase + (reg & 3) + 8 * (reg >> 2);
            if (row < N)
                Yr[(long)row * 64 + nt * 32 + col0] = __float2half_rn(acc[nt][reg]);
        }
    }
}

// ---- layer-2 gather: out[n] = bsum2 + sum_r rs_in*(sum_e coeff*Y2_r[s] + rs_out*Y2_r[n]).
// QUARTER-WAVE per edge: 16 lanes x uint2 = 128B row -> 4 edges/instr.
// One uniform predicated 32-edge window (8 loads in flight/lane).
// 2-step shfl reduce; lanes 0-15 store float4 (256B out row). ----
__global__ __launch_bounds__(256) void gather_out_kernel(const __half* __restrict__ Y2,
                                                         const float* __restrict__ rs_in,
                                                         const float* __restrict__ rs_out,
                                                         const int* __restrict__ row_ptr,
                                                         const unsigned int* __restrict__ esrc,
                                                         const float* __restrict__ bias,
                                                         float* __restrict__ outp) {
    int n = blockIdx.x * 4 + (threadIdx.x >> 6);
    if (n >= N) return;
    int lane = threadIdx.x & 63;
    int g = lane >> 4;                      // edge sub-slot 0..3
    int cl = lane & 15;                     // 4 cols: c = cl*4
    float4 tot = ((const float4*)bias)[cl];
#pragma unroll
    for (int r = 0; r < R; r++) {
        int key = r * N + n;
        const __half* Yr = Y2 + (long)r * N * 64;
        __half2 a0 = __float2half2_rn(0.f), a1 = a0;
        int beg = row_ptr[key], end = row_ptr[key + 1];
        for (int e = beg; e < end; e += 32) {
            unsigned u[8];
#pragma unroll
            for (int j = 0; j < 8; j++) {
                int idx = e + 4 * j + g;
                u[j] = (idx < end) ? esrc[idx] : 0u;
            }
            uint2 y[8];
#pragma unroll
            for (int j = 0; j < 8; j++)
                y[j] = *(const uint2*)(Yr + (long)(u[j] & 0xffffu) * 64 + cl * 4);
#pragma unroll
            for (int j = 0; j < 8; j++) {
                __half2 cj = __half2half2(__ushort_as_half((unsigned short)(u[j] >> 16)));
                a0 = __hfma2(*(__half2*)&y[j].x, cj, a0);
                a1 = __hfma2(*(__half2*)&y[j].y, cj, a1);
            }
        }
#pragma unroll
        for (int off = 16; off < 64; off <<= 1) {
            unsigned w0 = *(unsigned*)&a0, w1 = *(unsigned*)&a1;
            unsigned v0 = (unsigned)__shfl_xor((int)w0, off, 64);
            unsigned v1 = (unsigned)__shfl_xor((int)w1, off, 64);
            a0 = __hadd2(a0, *(__half2*)&v0);
            a1 = __hadd2(a1, *(__half2*)&v1);
        }
        // self-loop
        uint2 ys = *(const uint2*)(Yr + (long)n * 64 + cl * 4);
        __half2 cs = __float2half2_rn(rs_out[key]);
        a0 = __hfma2(*(__half2*)&ys.x, cs, a0);
        a1 = __hfma2(*(__half2*)&ys.y, cs, a1);
        float2 f0 = __half22float2(a0);
        float2 f1 = __half22float2(a1);
        float ri = rs_in[key];
        tot.x += ri * f0.x;
        tot.y += ri * f0.y;
        tot.z += ri * f1.x;
        tot.w += ri * f1.y;
    }
    if (g == 0) *(float4*)(outp + (long)n * 64 + cl * 4) = tot;
}

extern "C" void kernel_launch(void* const* d_in, const int* in_sizes, int n_in,
                              void* d_out, int out_size, void* d_ws, size_t ws_size,
                              hipStream_t stream) {
    const float* x  = (const float*)d_in[0];
    const int*  src = (const int*)d_in[1];
    const int*  dst = (const int*)d_in[2];
    const float* W1 = (const float*)d_in[3];   // [384][128]
    const float* b1 = (const float*)d_in[4];
    const float* W2 = (const float*)d_in[5];   // [384][64]
    const float* b2 = (const float*)d_in[6];
    float* out = (float*)d_out;
    const int E  = in_sizes[1] / R;
    const int RE = in_sizes[1];
    const int nb = (RE + CHUNK - 1) / CHUNK;      // 293 edge chunks
    const int L  = 2 * NBKT * nb;                 // ~86k
    const int nb1 = (L + 1023) / 1024;            // ~85

    char* ws = (char*)d_ws;
    size_t off = 0;
    auto alloc = [&](size_t bytes) -> void* {
        void* p = ws + off;
        off += (bytes + 255) & ~(size_t)255;
        return p;
    };
    float* bsum1    = (float*)alloc(HID * 4);
    float* bsum2    = (float*)alloc(OUT * 4);
    float* rs_in    = (float*)alloc((size_t)M * 4);
    float* rs_out   = (float*)alloc((size_t)M * 4);
    int*   row_ptr  = (int*)alloc((size_t)(M + 1) * 4);
    int*   bh       = (int*)alloc((size_t)L * 4);
    int*   scanv    = (int*)alloc((size_t)L * 4);
    int*   partials = (int*)alloc((size_t)nb1 * 4);
    unsigned* esrc  = (unsigned*)alloc((size_t)RE * 4);
    __half* F1      = (__half*)alloc((size_t)4 * KB * 64 * 8 * 2);
    __half* F2      = (__half*)alloc((size_t)2 * KB * 64 * 8 * 2);
    // region A: ebd(9.6MB)+ebs(4.8MB) during build; Z16 (38.4MB) for layer 1;
    // Y2 (19.2MB) for layer 2 (Z16 dead after gemm1).
    char*  regA     = (char*)alloc((size_t)N * 384 * 2);
    int*   ebd      = (int*)regA;
    unsigned short* ebs = (unsigned short*)(regA + (size_t)RE * 4);
    __half* Z16     = (__half*)regA;
    __half* Y2      = (__half*)regA;
    __half* x16     = (__half*)alloc((size_t)N * IN * 2);
    __half* H16     = (__half*)alloc((size_t)N * HID * 2);

    prep_kernel<<<1 + WPK_B + (CVT_N4 + 255) / 256, 256, 0, stream>>>(
        x, W1, W2, b1, b2, (uint2*)x16, F1, F2, bsum1, bsum2);
    p1_kernel<<<nb, 256, 0, stream>>>(src, dst, E, RE, nb, bh);
    scan1_kernel<<<nb1, 1024, 0, stream>>>(bh, scanv, partials, L);
    scan2_kernel<<<1, 256, 0, stream>>>(partials, nb1);
    p3_kernel<<<nb, 256, 0, stream>>>(src, dst, E, RE, nb, scanv, partials, ebd, ebs);
    pbs_kernel<<<NBKT, 1024, 0, stream>>>(scanv, partials, nb, RE, ebs, rs_out);
    pbd_kernel<<<NBKT, 1024, 0, stream>>>(scanv, partials, nb, RE, ebd, rs_out,
                                          row_ptr, rs_in, esrc);

    const int ab  = (N + 3) / 4;              // 12500 gather blocks
    const int ggb = (N + 127) / 128;          // 391 gemm blocks

    // layer 1: Z = gather(x16); H16 = fp16(relu(bsum1 + Z @ W1))
    gather_kernel<<<ab, 256, 0, stream>>>(x16, rs_in, rs_out, row_ptr, esrc, Z16);
    mfma_gemm1_kernel<<<ggb, 256, 0, stream>>>(Z16, F1, bsum1, H16);
    // layer 2 (GEMM-first): Y2_r = H16 @ W2_r; out = bsum2 + agg(Y2)
    mfma_gemmY_kernel<<<dim3(ggb, R), 256, 0, stream>>>(H16, F2, Y2);
    gather_out_kernel<<<ab, 256, 0, stream>>>(Y2, rs_in, rs_out, row_ptr, esrc,
                                              bsum2, out);
}